// Round 5
// baseline (133.840 us; speedup 1.0000x reference)
//
#include <hip/hip_runtime.h>
#include <hip/hip_bf16.h>
#include <math.h>

// ---------------- problem constants (B=1) ----------------
constexpr int NRIG = 512;
constexpr int NRES = 448;
constexpr int CS   = 384;
constexpr int CZ   = 128;
constexpr int CH   = 16;
constexpr int NH   = 12;
constexpr int PQ   = 4;
constexpr int PV   = 8;
constexpr int HC   = NH * CH;        // 192
constexpr int NPAIR = NRES*NRES;     // 200704
constexpr float INF_ = 100000.0f;

// ---------------- workspace layout (floats) ----------------
constexpr size_t OFF_Q   = 0;                                // [12][512][16]
constexpr size_t OFF_KT  = OFF_Q   + (size_t)NH*NRIG*16;     // [12][16][512]  transposed
constexpr size_t OFF_QP  = OFF_KT  + (size_t)NH*16*NRIG;     // [12][512][12]
constexpr size_t OFF_KPT = OFF_QP  + (size_t)NH*NRIG*12;     // [12][12][512]  transposed
constexpr size_t OFF_VT  = OFF_KPT + (size_t)NH*12*NRIG;     // [12][40][512]  (0..15 v, 16..39 vp)
constexpr size_t OFF_O   = OFF_VT  + (size_t)NH*40*NRIG;     // [512][12][16]
constexpr size_t OFF_OPT = OFF_O   + (size_t)NRIG*HC;        // [512][12][24]
constexpr size_t OFF_RS  = OFF_OPT + (size_t)NRIG*NH*PV*3;   // [512][12]
constexpr size_t OFF_BP  = OFF_RS  + (size_t)NRIG*NH;        // [200704][12] dense b_pair*sqrt(1/3)
// Aliases of the BP region (stream-ordered: raw -> bp -> feats F):
constexpr size_t OFF_RAW = OFF_BP;                           // [512][576] raw points (before zwb)
constexpr size_t OFF_F   = OFF_BP;                           // [512][960] feats (after attn)

// =====================================================================
// Kernel A1: tiled GEMM  C[512][1152] = s[512][384] @ W[384][1152]
// =====================================================================
__global__ __launch_bounds__(256) void proj_gemm_kernel(
    const float* __restrict__ s,
    const float* __restrict__ wq,  const float* __restrict__ bq,
    const float* __restrict__ wkv, const float* __restrict__ bkv,
    const float* __restrict__ wqp, const float* __restrict__ bqp,
    const float* __restrict__ wkvp,const float* __restrict__ bkvp,
    float* __restrict__ ws)
{
    constexpr int BM=64, BN=32, BK=32, LDA=68;
    __shared__ float sA[BK][LDA];
    __shared__ float sB[BK][BN];
    const int m0 = blockIdx.x * BM;
    const int c0 = blockIdx.y * BN;
    const int t  = threadIdx.x;
    const int tx = t & 15, ty = t >> 4;

    float acc[4][2] = {};

    for (int kt = 0; kt < CS/BK; ++kt) {
        const int k0 = kt*BK;
        #pragma unroll
        for (int r = 0; r < 2; ++r) {
            int qd = r*256 + t;
            int m = qd >> 3, kq = (qd & 7) << 2;
            float4 f = *(const float4*)(s + (size_t)(m0+m)*CS + k0 + kq);
            sA[kq+0][m] = f.x; sA[kq+1][m] = f.y;
            sA[kq+2][m] = f.z; sA[kq+3][m] = f.w;
        }
        {
            int kk = t >> 3, c4 = (t & 7) << 2;
            int c = c0 + c4;
            const float* wp; int ld, co;
            if (c < 192)      { wp = wq;   ld = 192; co = c;     }
            else if (c < 576) { wp = wkv;  ld = 384; co = c-192; }
            else if (c < 720) { wp = wqp;  ld = 144; co = c-576; }
            else              { wp = wkvp; ld = 432; co = c-720; }
            float4 f = *(const float4*)(wp + (size_t)(k0+kk)*ld + co);
            *(float4*)&sB[kk][c4] = f;
        }
        __syncthreads();
        #pragma unroll
        for (int kk = 0; kk < BK; ++kk) {
            float4 a = *(const float4*)&sA[kk][ty*4];
            float2 b = *(const float2*)&sB[kk][tx*2];
            acc[0][0] += a.x*b.x; acc[0][1] += a.x*b.y;
            acc[1][0] += a.y*b.x; acc[1][1] += a.y*b.y;
            acc[2][0] += a.z*b.x; acc[2][1] += a.z*b.y;
            acc[3][0] += a.w*b.x; acc[3][1] += a.w*b.y;
        }
        __syncthreads();
    }

    float* qw  = ws + OFF_Q;  float* ktw = ws + OFF_KT;  float* vt = ws + OFF_VT;
    float* raw = ws + OFF_RAW;
    #pragma unroll
    for (int i = 0; i < 4; ++i)
        #pragma unroll
        for (int j = 0; j < 2; ++j) {
            int n = m0 + ty*4 + i;
            int c = c0 + tx*2 + j;
            if (c < 192) {
                int hh = c >> 4, cc = c & 15;
                qw[((size_t)hh*NRIG + n)*16 + cc] = acc[i][j] + bq[c];
            } else if (c < 576) {
                int e = c-192; float val = acc[i][j] + bkv[e];
                int hh = e >> 5, sub = e & 31;
                if (sub < CH) ktw[((size_t)hh*16 + sub)*NRIG + n] = val;          // transposed K
                else          vt [((size_t)hh*40 + (sub-CH))*NRIG + n] = val;
            } else {
                int e = c-576;
                float bb_ = (c < 720) ? bqp[e] : bkvp[c-720];
                raw[(size_t)n*576 + e] = acc[i][j] + bb_;
            }
        }
}

// =====================================================================
// Kernel A2: rotate raw local points -> global frame
// q_pts -> QP[h][n][12]; k_pts -> KPT[h][12][512] (transposed); v_pts -> VT
// =====================================================================
__global__ __launch_bounds__(256) void rotate_kernel(
    const float* __restrict__ rot, const float* __restrict__ trans,
    float* __restrict__ ws)
{
    const int gid = blockIdx.x*256 + threadIdx.x;
    const int n = gid / 192, d = gid % 192;
    const float* raw = ws + OFF_RAW + (size_t)n*576;
    float px, py, pzz;
    if (d < 48) { px = raw[d];      py = raw[48+d];       pzz = raw[96+d]; }
    else { int dd = d-48; px = raw[144+dd]; py = raw[288+dd]; pzz = raw[432+dd]; }
    const float* R = rot   + (size_t)n*9;
    const float* T = trans + (size_t)n*3;
    float gx = R[0]*px + R[1]*py + R[2]*pzz + T[0];
    float gy = R[3]*px + R[4]*py + R[5]*pzz + T[1];
    float gz = R[6]*px + R[7]*py + R[8]*pzz + T[2];
    if (d < 48) {                              // q_pts: d = h*4+p
        int hh = d >> 2, pp = d & 3;
        float* dst = ws + OFF_QP + ((size_t)hh*NRIG + n)*12 + pp*3;
        dst[0]=gx; dst[1]=gy; dst[2]=gz;
    } else {
        int dd = d-48; int hh = dd/12, pp = dd%12;  // kv_pts
        if (pp < PQ) {
            float* kpt = ws + OFF_KPT + (size_t)hh*12*NRIG;
            kpt[(size_t)(pp*3+0)*NRIG + n] = gx;
            kpt[(size_t)(pp*3+1)*NRIG + n] = gy;
            kpt[(size_t)(pp*3+2)*NRIG + n] = gz;
        } else {
            float* vt = ws + OFF_VT + ((size_t)hh*40 + 16 + (pp-PQ)*3)*NRIG + n;
            vt[0*NRIG]=gx; vt[1*NRIG]=gy; vt[2*NRIG]=gz;
        }
    }
}

// =====================================================================
// Kernel B: dense b_pair GEMM  bp[448*448][12] = (z @ w_b + b_b)*sqrt(1/3)
// Linear streaming of z (no gather). block = 64 rows, 256 threads.
// =====================================================================
__global__ __launch_bounds__(256) void zwb_kernel(
    const float* __restrict__ z,
    const float* __restrict__ wb, const float* __restrict__ bb,
    float* __restrict__ ws)
{
    constexpr int BR = 64, LDZ = 132;
    __shared__ float sZ[BR][LDZ];
    __shared__ float sW[CZ*12];
    const int t = threadIdx.x;
    const size_t r0 = (size_t)blockIdx.x * BR;

    for (int e = t; e < CZ*12; e += 256) sW[e] = wb[e];
    #pragma unroll
    for (int p = 0; p < 8; ++p) {
        int q = p*256 + t;
        int r = q >> 5, c4 = (q & 31) << 2;
        float4 f = *(const float4*)(z + (r0 + r)*CZ + c4);
        *(float4*)&sZ[r][c4] = f;
    }
    __syncthreads();

    const int r = t >> 2, g = t & 3;
    float a0=0.f, a1=0.f, a2=0.f;
    #pragma unroll 8
    for (int c = 0; c < CZ; ++c) {
        float zv = sZ[r][c];
        const float* w = &sW[c*12 + g*3];
        a0 += zv*w[0]; a1 += zv*w[1]; a2 += zv*w[2];
    }
    const float SC = 0.57735026918962584f;   // sqrt(1/3)
    float* bp = ws + OFF_BP + (r0 + r)*12 + g*3;
    bp[0] = (a0 + bb[g*3+0])*SC;
    bp[1] = (a1 + bb[g*3+1])*SC;
    bp[2] = (a2 + bb[g*3+2])*SC;
}

// =====================================================================
// Kernel C: attention. block = (h, 4 queries), 256 threads.
// Phase 1: coalesced transposed K/KP loads + bp gather. Phase 2: VT GEMM.
// =====================================================================
__global__ __launch_bounds__(256) void attn_kernel(
    const float* __restrict__ hw_in, const float* __restrict__ mask,
    const int* __restrict__ ridx,
    float* __restrict__ ws)
{
    constexpr int TI = 4;
    const int h    = blockIdx.x;
    const int i0   = blockIdx.y * TI;
    const int t    = threadIdx.x;
    const int lane = t & 63, wid = t >> 6;

    __shared__ float sQ[TI][16];
    __shared__ float sQP[TI][12];
    __shared__ float sE[TI][512];
    __shared__ float redM[TI][4], redS[TI][4];
    __shared__ float sMi[TI];
    __shared__ int   sRi[TI];
    __shared__ float sP[TI][16][44];

    const float* qw  = ws + OFF_Q   + (size_t)h*NRIG*16;
    const float* ktw = ws + OFF_KT  + (size_t)h*16*NRIG;
    const float* qpw = ws + OFF_QP  + (size_t)h*NRIG*12;
    const float* kpt = ws + OFF_KPT + (size_t)h*12*NRIG;
    const float* vt  = ws + OFF_VT  + (size_t)h*40*NRIG;
    const float* bp  = ws + OFF_BP;

    for (int e = t; e < TI*16; e += 256) sQ[e/16][e%16]  = qw[(size_t)(i0+e/16)*16 + (e%16)];
    for (int e = t; e < TI*12; e += 256) sQP[e/12][e%12] = qpw[(size_t)(i0+e/12)*12 + (e%12)];
    if (t < TI) { sMi[t] = mask[i0+t]; sRi[t] = ridx[i0+t]; }
    __syncthreads();

    const float hwv = -0.5f * log1pf(__expf(hw_in[h])) * 0.13608276348795434f; // -0.5*softplus*sqrt(1/54)
    const float QKS = 0.14433756729740643f;                                    // sqrt(1/48)

    float lg[2][TI];
    float lmax[TI] = {-1e30f,-1e30f,-1e30f,-1e30f};
    #pragma unroll
    for (int jj = 0; jj < 2; ++jj) {
        int j = t + jj*256;
        float kk[16], kpv[12];
        #pragma unroll
        for (int c = 0; c < 16; ++c) kk[c]  = ktw[(size_t)c*NRIG + j];   // coalesced
        #pragma unroll
        for (int e = 0; e < 12; ++e) kpv[e] = kpt[(size_t)e*NRIG + j];   // coalesced
        float mj = mask[j];
        int rj = ridx[j];
        #pragma unroll
        for (int qq = 0; qq < TI; ++qq) {
            float dot = 0.f;
            #pragma unroll
            for (int c = 0; c < 16; ++c) dot += sQ[qq][c]*kk[c];
            float sq = 0.f;
            #pragma unroll
            for (int e = 0; e < 12; ++e) { float d = sQP[qq][e]-kpv[e]; sq += d*d; }
            float bv = bp[((size_t)sRi[qq]*NRES + rj)*12 + h];
            float lgt = dot*QKS + bv + hwv*sq + INF_*(sMi[qq]*mj - 1.0f);
            lg[jj][qq] = lgt;
            lmax[qq] = fmaxf(lmax[qq], lgt);
        }
    }
    #pragma unroll
    for (int sft = 1; sft < 64; sft <<= 1)
        #pragma unroll
        for (int qq=0;qq<TI;++qq) lmax[qq] = fmaxf(lmax[qq], __shfl_xor(lmax[qq], sft));
    if (lane == 0) { for (int qq=0;qq<TI;++qq) redM[qq][wid] = lmax[qq]; }
    __syncthreads();
    float M[TI], psum[TI];
    #pragma unroll
    for (int qq=0;qq<TI;++qq) {
        M[qq] = fmaxf(fmaxf(redM[qq][0],redM[qq][1]),fmaxf(redM[qq][2],redM[qq][3]));
        psum[qq]=0.f;
    }
    #pragma unroll
    for (int jj = 0; jj < 2; ++jj) {
        int j = t + jj*256;
        #pragma unroll
        for (int qq=0;qq<TI;++qq) {
            float e = __expf(lg[jj][qq] - M[qq]);
            sE[qq][j] = e;
            psum[qq] += e;
        }
    }
    #pragma unroll
    for (int sft = 1; sft < 64; sft <<= 1)
        #pragma unroll
        for (int qq=0;qq<TI;++qq) psum[qq] += __shfl_xor(psum[qq], sft);
    if (lane == 0) { for (int qq=0;qq<TI;++qq) redS[qq][wid] = psum[qq]; }
    __syncthreads();

    {
        const int c0 = wid*10;
        float acc[10][TI];
        #pragma unroll
        for (int ci=0;ci<10;++ci)
            #pragma unroll
            for (int qq=0;qq<TI;++qq) acc[ci][qq]=0.f;

        #pragma unroll
        for (int m = 0; m < 8; ++m) {
            const int j = lane + 64*m;
            float ev[TI];
            #pragma unroll
            for (int qq=0;qq<TI;++qq) ev[qq] = sE[qq][j];
            #pragma unroll
            for (int ci = 0; ci < 10; ++ci) {
                float vv = vt[(size_t)(c0+ci)*NRIG + j];
                #pragma unroll
                for (int qq=0;qq<TI;++qq) acc[ci][qq] += ev[qq]*vv;
            }
        }
        #pragma unroll
        for (int ci=0;ci<10;++ci)
            #pragma unroll
            for (int qq=0;qq<TI;++qq) {
                acc[ci][qq] += __shfl_xor(acc[ci][qq], 1);
                acc[ci][qq] += __shfl_xor(acc[ci][qq], 2);
            }
        if ((lane & 3) == 0) {
            const int g = lane >> 2;
            #pragma unroll
            for (int qq=0;qq<TI;++qq)
                #pragma unroll
                for (int ci=0;ci<10;++ci)
                    sP[qq][g][c0+ci] = acc[ci][qq];
        }
    }
    __syncthreads();

    if (t < TI*41) {
        const int qq = t / 41, c = t % 41;
        const int n = i0 + qq;
        float S = redS[qq][0]+redS[qq][1]+redS[qq][2]+redS[qq][3];
        float Sinv = 1.0f / S;
        if (c == 40) {
            (ws + OFF_RS)[(size_t)n*NH + h] = S * Sinv;
        } else {
            float acc = 0.f;
            #pragma unroll
            for (int g = 0; g < 16; ++g) acc += sP[qq][g][c];
            acc *= Sinv;
            if (c < 16) (ws + OFF_O  )[((size_t)n*NH + h)*CH + c]      = acc;
            else        (ws + OFF_OPT)[((size_t)n*NH + h)*24 + (c-16)] = acc;
        }
    }
}

// =====================================================================
// Kernel D1: build feats F[512][960] (o | o_pt xyz | norm | o_pair)
// includes pz_diag = z[ri,ri,:] @ w_dz + b_dz computed in-block.
// =====================================================================
__global__ __launch_bounds__(256) void feats_kernel(
    const float* __restrict__ rot, const float* __restrict__ trans,
    const float* __restrict__ z, const int* __restrict__ ridx,
    const float* __restrict__ wdz, const float* __restrict__ bdz,
    float* __restrict__ ws)
{
    constexpr int TI = 4;
    __shared__ float sZd[TI][CZ];
    __shared__ float sPz[TI][32];
    const int i0 = blockIdx.x*TI;
    const int t  = threadIdx.x;
    float* F = ws + OFF_F;
    const float* o_ws = ws + OFF_O;  const float* optg = ws + OFF_OPT;
    const float* rs   = ws + OFF_RS;

    // stage diag z rows
    for (int e = t; e < TI*CZ; e += 256) {
        int qq = e >> 7, c = e & 127;
        int ri = ridx[i0+qq];
        sZd[qq][c] = z[((size_t)ri*NRES + ri)*CZ + c];
    }
    // o copy
    for (int e = t; e < TI*HC; e += 256) {
        int qq = e/HC, c = e%HC;
        F[(size_t)(i0+qq)*960 + c] = o_ws[(size_t)(i0+qq)*HC + c];
    }
    // o_pt rotate-back + norm
    for (int e = t; e < TI*96; e += 256) {
        int qq = e/96, hp = e%96; int n = i0+qq;
        const float* g = optg + ((size_t)n*NH + hp/PV)*24 + (hp%PV)*3;
        float gx = g[0]-trans[n*3+0], gy = g[1]-trans[n*3+1], gz = g[2]-trans[n*3+2];
        const float* R = rot + (size_t)n*9;
        float lx = R[0]*gx + R[3]*gy + R[6]*gz;   // rot^T
        float ly = R[1]*gx + R[4]*gy + R[7]*gz;
        float lz = R[2]*gx + R[5]*gy + R[8]*gz;
        float* Fr = F + (size_t)n*960;
        Fr[192+hp] = lx; Fr[288+hp] = ly; Fr[384+hp] = lz;
        Fr[480+hp] = sqrtf(lx*lx+ly*ly+lz*lz + 1e-8f);
    }
    __syncthreads();
    // pz_diag: 4 rigids x 32 outputs, K=128
    if (t < TI*32) {
        int qq = t >> 5, d = t & 31;
        float acc = 0.f;
        #pragma unroll 8
        for (int c = 0; c < CZ; ++c) acc += sZd[qq][c] * wdz[(size_t)c*32 + d];
        sPz[qq][d] = acc + bdz[d];
    }
    __syncthreads();
    // o_pair
    for (int e = t; e < TI*384; e += 256) {
        int qq = e/384, hd = e%384; int n = i0+qq;
        F[(size_t)n*960 + 576 + hd] = rs[(size_t)n*NH + (hd>>5)] * sPz[qq][hd&31];
    }
}

// =====================================================================
// Kernel D2: tiled GEMM  out[512][384] = F[512][960] @ w_out + b_out
// BM=32 BN=16 BK=32 -> grid 16x24 = 384 blocks (2 outputs/thread).
// =====================================================================
__global__ __launch_bounds__(256) void out_gemm_kernel(
    const float* __restrict__ w_out, const float* __restrict__ b_out,
    const float* __restrict__ ws, float* __restrict__ out)
{
    constexpr int BM=32, BN=16, BK=32, LDA=36;
    __shared__ float sA[BK][LDA];
    __shared__ float sB[BK][BN];
    const float* F = ws + OFF_F;
    const int m0 = blockIdx.x * BM;
    const int c0 = blockIdx.y * BN;
    const int t  = threadIdx.x;
    const int tx = t & 15, ty = t >> 4;

    float acc0 = 0.f, acc1 = 0.f;

    for (int kt = 0; kt < 960/BK; ++kt) {
        const int k0 = kt*BK;
        {   // stage A: 32 rows x 8 f4, 1 f4/thread
            int m = t >> 3, kq = (t & 7) << 2;
            float4 f = *(const float4*)(F + (size_t)(m0+m)*960 + k0 + kq);
            sA[kq+0][m] = f.x; sA[kq+1][m] = f.y;
            sA[kq+2][m] = f.z; sA[kq+3][m] = f.w;
        }
        if (t < 128) {  // stage B: 32 rows x 4 f4
            int kk = t >> 2, c4 = (t & 3) << 2;
            float4 f = *(const float4*)(w_out + (size_t)(k0+kk)*CS + c0 + c4);
            *(float4*)&sB[kk][c4] = f;
        }
        __syncthreads();
        #pragma unroll
        for (int kk = 0; kk < BK; ++kk) {
            float b  = sB[kk][tx];
            acc0 += sA[kk][ty*2+0]*b;
            acc1 += sA[kk][ty*2+1]*b;
        }
        __syncthreads();
    }

    const int c = c0 + tx;
    const float bv = b_out[c];
    out[(size_t)(m0 + ty*2+0)*CS + c] = acc0 + bv;
    out[(size_t)(m0 + ty*2+1)*CS + c] = acc1 + bv;
}

// =====================================================================
extern "C" void kernel_launch(void* const* d_in, const int* in_sizes, int n_in,
                              void* d_out, int out_size, void* d_ws, size_t ws_size,
                              hipStream_t stream)
{
    const float* s     = (const float*)d_in[0];
    const float* z     = (const float*)d_in[1];
    const float* rot   = (const float*)d_in[2];
    const float* trans = (const float*)d_in[3];
    const float* mask  = (const float*)d_in[4];
    const int*   ridx  = (const int*)  d_in[5];
    const float* wq    = (const float*)d_in[6];
    const float* bq    = (const float*)d_in[7];
    const float* wkv   = (const float*)d_in[8];
    const float* bkv   = (const float*)d_in[9];
    const float* wqp   = (const float*)d_in[10];
    const float* bqp   = (const float*)d_in[11];
    const float* wkvp  = (const float*)d_in[12];
    const float* bkvp  = (const float*)d_in[13];
    const float* wb    = (const float*)d_in[14];
    const float* bb    = (const float*)d_in[15];
    const float* wdz   = (const float*)d_in[16];
    const float* bdz   = (const float*)d_in[17];
    const float* hw    = (const float*)d_in[18];
    const float* wout  = (const float*)d_in[19];
    const float* bout  = (const float*)d_in[20];
    float* ws  = (float*)d_ws;
    float* out = (float*)d_out;

    hipLaunchKernelGGL(proj_gemm_kernel, dim3(NRIG/64, 1152/32), dim3(256), 0, stream,
        s, wq,bq, wkv,bkv, wqp,bqp, wkvp,bkvp, ws);
    hipLaunchKernelGGL(rotate_kernel, dim3(NRIG*192/256), dim3(256), 0, stream,
        rot, trans, ws);
    hipLaunchKernelGGL(zwb_kernel, dim3(NPAIR/64), dim3(256), 0, stream,
        z, wb, bb, ws);
    hipLaunchKernelGGL(attn_kernel, dim3(NH, NRIG/4), dim3(256), 0, stream,
        hw, mask, ridx, ws);
    hipLaunchKernelGGL(feats_kernel, dim3(NRIG/4), dim3(256), 0, stream,
        rot, trans, z, ridx, wdz, bdz, ws);
    hipLaunchKernelGGL(out_gemm_kernel, dim3(NRIG/32, CS/16), dim3(256), 0, stream,
        wout, bout, ws, out);
}

// Round 6
// 127.252 us; speedup vs baseline: 1.0518x; 1.0518x over previous
//
#include <hip/hip_runtime.h>
#include <hip/hip_bf16.h>
#include <math.h>

// ---------------- problem constants (B=1) ----------------
constexpr int NRIG = 512;
constexpr int NRES = 448;
constexpr int CS   = 384;
constexpr int CZ   = 128;
constexpr int CH   = 16;
constexpr int NH   = 12;
constexpr int PQ   = 4;
constexpr int PV   = 8;
constexpr int HC   = NH * CH;        // 192
constexpr int NPAIR = NRES*NRES;     // 200704
constexpr float INF_ = 100000.0f;

// ---------------- workspace layout (floats) ----------------
constexpr size_t OFF_Q   = 0;                                // [12][512][16]
constexpr size_t OFF_KT  = OFF_Q   + (size_t)NH*NRIG*16;     // [12][16][512]  transposed
constexpr size_t OFF_QP  = OFF_KT  + (size_t)NH*16*NRIG;     // [12][512][12]
constexpr size_t OFF_KPT = OFF_QP  + (size_t)NH*NRIG*12;     // [12][12][512]  transposed
constexpr size_t OFF_VT  = OFF_KPT + (size_t)NH*12*NRIG;     // [12][40][512]  (0..15 v, 16..39 vp)
constexpr size_t OFF_O   = OFF_VT  + (size_t)NH*40*NRIG;     // [512][12][16]
constexpr size_t OFF_OPT = OFF_O   + (size_t)NRIG*HC;        // [512][12][24]
constexpr size_t OFF_RS  = OFF_OPT + (size_t)NRIG*NH*PV*3;   // [512][12]
constexpr size_t OFF_BP  = OFF_RS  + (size_t)NRIG*NH;        // [12][448*448] h-major planes
// Aliases of the BP region (stream-ordered: raw -> bp -> feats F):
constexpr size_t OFF_RAW = OFF_BP;                           // [512][576] raw points (before zwb)
constexpr size_t OFF_F   = OFF_BP;                           // [512][960] feats (after attn)

// =====================================================================
// Kernel A1: tiled GEMM  C[512][1152] = s[512][384] @ W[384][1152]
// =====================================================================
__global__ __launch_bounds__(256) void proj_gemm_kernel(
    const float* __restrict__ s,
    const float* __restrict__ wq,  const float* __restrict__ bq,
    const float* __restrict__ wkv, const float* __restrict__ bkv,
    const float* __restrict__ wqp, const float* __restrict__ bqp,
    const float* __restrict__ wkvp,const float* __restrict__ bkvp,
    float* __restrict__ ws)
{
    constexpr int BM=64, BN=32, BK=32, LDA=68;
    __shared__ float sA[BK][LDA];
    __shared__ float sB[BK][BN];
    const int m0 = blockIdx.x * BM;
    const int c0 = blockIdx.y * BN;
    const int t  = threadIdx.x;
    const int tx = t & 15, ty = t >> 4;

    float acc[4][2] = {};

    for (int kt = 0; kt < CS/BK; ++kt) {
        const int k0 = kt*BK;
        #pragma unroll
        for (int r = 0; r < 2; ++r) {
            int qd = r*256 + t;
            int m = qd >> 3, kq = (qd & 7) << 2;
            float4 f = *(const float4*)(s + (size_t)(m0+m)*CS + k0 + kq);
            sA[kq+0][m] = f.x; sA[kq+1][m] = f.y;
            sA[kq+2][m] = f.z; sA[kq+3][m] = f.w;
        }
        {
            int kk = t >> 3, c4 = (t & 7) << 2;
            int c = c0 + c4;
            const float* wp; int ld, co;
            if (c < 192)      { wp = wq;   ld = 192; co = c;     }
            else if (c < 576) { wp = wkv;  ld = 384; co = c-192; }
            else if (c < 720) { wp = wqp;  ld = 144; co = c-576; }
            else              { wp = wkvp; ld = 432; co = c-720; }
            float4 f = *(const float4*)(wp + (size_t)(k0+kk)*ld + co);
            *(float4*)&sB[kk][c4] = f;
        }
        __syncthreads();
        #pragma unroll
        for (int kk = 0; kk < BK; ++kk) {
            float4 a = *(const float4*)&sA[kk][ty*4];
            float2 b = *(const float2*)&sB[kk][tx*2];
            acc[0][0] += a.x*b.x; acc[0][1] += a.x*b.y;
            acc[1][0] += a.y*b.x; acc[1][1] += a.y*b.y;
            acc[2][0] += a.z*b.x; acc[2][1] += a.z*b.y;
            acc[3][0] += a.w*b.x; acc[3][1] += a.w*b.y;
        }
        __syncthreads();
    }

    float* qw  = ws + OFF_Q;  float* ktw = ws + OFF_KT;  float* vt = ws + OFF_VT;
    float* raw = ws + OFF_RAW;
    #pragma unroll
    for (int i = 0; i < 4; ++i)
        #pragma unroll
        for (int j = 0; j < 2; ++j) {
            int n = m0 + ty*4 + i;
            int c = c0 + tx*2 + j;
            if (c < 192) {
                int hh = c >> 4, cc = c & 15;
                qw[((size_t)hh*NRIG + n)*16 + cc] = acc[i][j] + bq[c];
            } else if (c < 576) {
                int e = c-192; float val = acc[i][j] + bkv[e];
                int hh = e >> 5, sub = e & 31;
                if (sub < CH) ktw[((size_t)hh*16 + sub)*NRIG + n] = val;          // transposed K
                else          vt [((size_t)hh*40 + (sub-CH))*NRIG + n] = val;
            } else {
                int e = c-576;
                float bb_ = (c < 720) ? bqp[e] : bkvp[c-720];
                raw[(size_t)n*576 + e] = acc[i][j] + bb_;
            }
        }
}

// =====================================================================
// Kernel A2: rotate raw local points -> global frame
// =====================================================================
__global__ __launch_bounds__(256) void rotate_kernel(
    const float* __restrict__ rot, const float* __restrict__ trans,
    float* __restrict__ ws)
{
    const int gid = blockIdx.x*256 + threadIdx.x;
    const int n = gid / 192, d = gid % 192;
    const float* raw = ws + OFF_RAW + (size_t)n*576;
    float px, py, pzz;
    if (d < 48) { px = raw[d];      py = raw[48+d];       pzz = raw[96+d]; }
    else { int dd = d-48; px = raw[144+dd]; py = raw[288+dd]; pzz = raw[432+dd]; }
    const float* R = rot   + (size_t)n*9;
    const float* T = trans + (size_t)n*3;
    float gx = R[0]*px + R[1]*py + R[2]*pzz + T[0];
    float gy = R[3]*px + R[4]*py + R[5]*pzz + T[1];
    float gz = R[6]*px + R[7]*py + R[8]*pzz + T[2];
    if (d < 48) {                              // q_pts: d = h*4+p
        int hh = d >> 2, pp = d & 3;
        float* dst = ws + OFF_QP + ((size_t)hh*NRIG + n)*12 + pp*3;
        dst[0]=gx; dst[1]=gy; dst[2]=gz;
    } else {
        int dd = d-48; int hh = dd/12, pp = dd%12;  // kv_pts
        if (pp < PQ) {
            float* kpt = ws + OFF_KPT + (size_t)hh*12*NRIG;
            kpt[(size_t)(pp*3+0)*NRIG + n] = gx;
            kpt[(size_t)(pp*3+1)*NRIG + n] = gy;
            kpt[(size_t)(pp*3+2)*NRIG + n] = gz;
        } else {
            float* vt = ws + OFF_VT + ((size_t)hh*40 + 16 + (pp-PQ)*3)*NRIG + n;
            vt[0*NRIG]=gx; vt[1*NRIG]=gy; vt[2*NRIG]=gz;
        }
    }
}

// =====================================================================
// Kernel B: dense b_pair GEMM, h-major planes:
//   bp[h][448*448] = (z @ w_b + b_b)[:, h] * sqrt(1/3)
// Linear streaming of z. block = 64 pair-rows, 256 threads.
// =====================================================================
__global__ __launch_bounds__(256) void zwb_kernel(
    const float* __restrict__ z,
    const float* __restrict__ wb, const float* __restrict__ bb,
    float* __restrict__ ws)
{
    constexpr int BR = 64, LDZ = 132;
    __shared__ float sZ[BR][LDZ];
    __shared__ float sW[CZ*12];
    const int t = threadIdx.x;
    const size_t r0 = (size_t)blockIdx.x * BR;

    for (int e = t; e < CZ*12; e += 256) sW[e] = wb[e];
    #pragma unroll
    for (int p = 0; p < 8; ++p) {
        int q = p*256 + t;
        int r = q >> 5, c4 = (q & 31) << 2;
        float4 f = *(const float4*)(z + (r0 + r)*CZ + c4);
        *(float4*)&sZ[r][c4] = f;
    }
    __syncthreads();

    const int r = t >> 2, g = t & 3;       // thread: pair-row r, h-group g (3 h's)
    float a0=0.f, a1=0.f, a2=0.f;
    #pragma unroll 8
    for (int c = 0; c < CZ; ++c) {
        float zv = sZ[r][c];
        const float* w = &sW[c*12 + g*3];
        a0 += zv*w[0]; a1 += zv*w[1]; a2 += zv*w[2];
    }
    const float SC = 0.57735026918962584f;   // sqrt(1/3)
    float* bp = ws + OFF_BP;
    bp[(size_t)(g*3+0)*NPAIR + r0 + r] = (a0 + bb[g*3+0])*SC;
    bp[(size_t)(g*3+1)*NPAIR + r0 + r] = (a1 + bb[g*3+1])*SC;
    bp[(size_t)(g*3+2)*NPAIR + r0 + r] = (a2 + bb[g*3+2])*SC;
}

// =====================================================================
// Kernel C: attention. block = (h, 4 queries), 256 threads.
// Phase 1: coalesced transposed K/KP loads; bias gathered from the h-plane
// of bp — per-qq window is one 1792B res-row (L1-resident).
// =====================================================================
__global__ __launch_bounds__(256) void attn_kernel(
    const float* __restrict__ hw_in, const float* __restrict__ mask,
    const int* __restrict__ ridx,
    float* __restrict__ ws)
{
    constexpr int TI = 4;
    const int h    = blockIdx.x;
    const int i0   = blockIdx.y * TI;
    const int t    = threadIdx.x;
    const int lane = t & 63, wid = t >> 6;

    __shared__ float sQ[TI][16];
    __shared__ float sQP[TI][12];
    __shared__ float sE[TI][512];
    __shared__ float redM[TI][4], redS[TI][4];
    __shared__ float sMi[TI];
    __shared__ int   sRi[TI];
    __shared__ float sP[TI][16][44];

    const float* qw  = ws + OFF_Q   + (size_t)h*NRIG*16;
    const float* ktw = ws + OFF_KT  + (size_t)h*16*NRIG;
    const float* qpw = ws + OFF_QP  + (size_t)h*NRIG*12;
    const float* kpt = ws + OFF_KPT + (size_t)h*12*NRIG;
    const float* vt  = ws + OFF_VT  + (size_t)h*40*NRIG;
    const float* bph = ws + OFF_BP  + (size_t)h*NPAIR;

    for (int e = t; e < TI*16; e += 256) sQ[e/16][e%16]  = qw[(size_t)(i0+e/16)*16 + (e%16)];
    for (int e = t; e < TI*12; e += 256) sQP[e/12][e%12] = qpw[(size_t)(i0+e/12)*12 + (e%12)];
    if (t < TI) { sMi[t] = mask[i0+t]; sRi[t] = ridx[i0+t]; }
    __syncthreads();

    const float hwv = -0.5f * log1pf(__expf(hw_in[h])) * 0.13608276348795434f; // -0.5*softplus*sqrt(1/54)
    const float QKS = 0.14433756729740643f;                                    // sqrt(1/48)

    float lg[2][TI];
    float lmax[TI] = {-1e30f,-1e30f,-1e30f,-1e30f};
    #pragma unroll
    for (int jj = 0; jj < 2; ++jj) {
        int j = t + jj*256;
        float kk[16], kpv[12];
        #pragma unroll
        for (int c = 0; c < 16; ++c) kk[c]  = ktw[(size_t)c*NRIG + j];   // coalesced
        #pragma unroll
        for (int e = 0; e < 12; ++e) kpv[e] = kpt[(size_t)e*NRIG + j];   // coalesced
        float mj = mask[j];
        int rj = ridx[j];
        float bv[TI];
        #pragma unroll
        for (int qq = 0; qq < TI; ++qq)
            bv[qq] = bph[(size_t)sRi[qq]*NRES + rj];    // 1792B window, L1-hot
        #pragma unroll
        for (int qq = 0; qq < TI; ++qq) {
            float dot = 0.f;
            #pragma unroll
            for (int c = 0; c < 16; ++c) dot += sQ[qq][c]*kk[c];
            float sq = 0.f;
            #pragma unroll
            for (int e = 0; e < 12; ++e) { float d = sQP[qq][e]-kpv[e]; sq += d*d; }
            float lgt = dot*QKS + bv[qq] + hwv*sq + INF_*(sMi[qq]*mj - 1.0f);
            lg[jj][qq] = lgt;
            lmax[qq] = fmaxf(lmax[qq], lgt);
        }
    }
    #pragma unroll
    for (int sft = 1; sft < 64; sft <<= 1)
        #pragma unroll
        for (int qq=0;qq<TI;++qq) lmax[qq] = fmaxf(lmax[qq], __shfl_xor(lmax[qq], sft));
    if (lane == 0) { for (int qq=0;qq<TI;++qq) redM[qq][wid] = lmax[qq]; }
    __syncthreads();
    float M[TI], psum[TI];
    #pragma unroll
    for (int qq=0;qq<TI;++qq) {
        M[qq] = fmaxf(fmaxf(redM[qq][0],redM[qq][1]),fmaxf(redM[qq][2],redM[qq][3]));
        psum[qq]=0.f;
    }
    #pragma unroll
    for (int jj = 0; jj < 2; ++jj) {
        int j = t + jj*256;
        #pragma unroll
        for (int qq=0;qq<TI;++qq) {
            float e = __expf(lg[jj][qq] - M[qq]);
            sE[qq][j] = e;
            psum[qq] += e;
        }
    }
    #pragma unroll
    for (int sft = 1; sft < 64; sft <<= 1)
        #pragma unroll
        for (int qq=0;qq<TI;++qq) psum[qq] += __shfl_xor(psum[qq], sft);
    if (lane == 0) { for (int qq=0;qq<TI;++qq) redS[qq][wid] = psum[qq]; }
    __syncthreads();

    {
        const int c0 = wid*10;
        float acc[10][TI];
        #pragma unroll
        for (int ci=0;ci<10;++ci)
            #pragma unroll
            for (int qq=0;qq<TI;++qq) acc[ci][qq]=0.f;

        #pragma unroll
        for (int m = 0; m < 8; ++m) {
            const int j = lane + 64*m;
            float ev[TI];
            #pragma unroll
            for (int qq=0;qq<TI;++qq) ev[qq] = sE[qq][j];
            #pragma unroll
            for (int ci = 0; ci < 10; ++ci) {
                float vv = vt[(size_t)(c0+ci)*NRIG + j];
                #pragma unroll
                for (int qq=0;qq<TI;++qq) acc[ci][qq] += ev[qq]*vv;
            }
        }
        #pragma unroll
        for (int ci=0;ci<10;++ci)
            #pragma unroll
            for (int qq=0;qq<TI;++qq) {
                acc[ci][qq] += __shfl_xor(acc[ci][qq], 1);
                acc[ci][qq] += __shfl_xor(acc[ci][qq], 2);
            }
        if ((lane & 3) == 0) {
            const int g = lane >> 2;
            #pragma unroll
            for (int qq=0;qq<TI;++qq)
                #pragma unroll
                for (int ci=0;ci<10;++ci)
                    sP[qq][g][c0+ci] = acc[ci][qq];
        }
    }
    __syncthreads();

    if (t < TI*41) {
        const int qq = t / 41, c = t % 41;
        const int n = i0 + qq;
        float S = redS[qq][0]+redS[qq][1]+redS[qq][2]+redS[qq][3];
        float Sinv = 1.0f / S;
        if (c == 40) {
            (ws + OFF_RS)[(size_t)n*NH + h] = S * Sinv;
        } else {
            float acc = 0.f;
            #pragma unroll
            for (int g = 0; g < 16; ++g) acc += sP[qq][g][c];
            acc *= Sinv;
            if (c < 16) (ws + OFF_O  )[((size_t)n*NH + h)*CH + c]      = acc;
            else        (ws + OFF_OPT)[((size_t)n*NH + h)*24 + (c-16)] = acc;
        }
    }
}

// =====================================================================
// Kernel D1: build feats F[512][960]; pz_diag computed in-block.
// =====================================================================
__global__ __launch_bounds__(256) void feats_kernel(
    const float* __restrict__ rot, const float* __restrict__ trans,
    const float* __restrict__ z, const int* __restrict__ ridx,
    const float* __restrict__ wdz, const float* __restrict__ bdz,
    float* __restrict__ ws)
{
    constexpr int TI = 4;
    __shared__ float sZd[TI][CZ];
    __shared__ float sPz[TI][32];
    const int i0 = blockIdx.x*TI;
    const int t  = threadIdx.x;
    float* F = ws + OFF_F;
    const float* o_ws = ws + OFF_O;  const float* optg = ws + OFF_OPT;
    const float* rs   = ws + OFF_RS;

    for (int e = t; e < TI*CZ; e += 256) {
        int qq = e >> 7, c = e & 127;
        int ri = ridx[i0+qq];
        sZd[qq][c] = z[((size_t)ri*NRES + ri)*CZ + c];
    }
    for (int e = t; e < TI*HC; e += 256) {
        int qq = e/HC, c = e%HC;
        F[(size_t)(i0+qq)*960 + c] = o_ws[(size_t)(i0+qq)*HC + c];
    }
    for (int e = t; e < TI*96; e += 256) {
        int qq = e/96, hp = e%96; int n = i0+qq;
        const float* g = optg + ((size_t)n*NH + hp/PV)*24 + (hp%PV)*3;
        float gx = g[0]-trans[n*3+0], gy = g[1]-trans[n*3+1], gz = g[2]-trans[n*3+2];
        const float* R = rot + (size_t)n*9;
        float lx = R[0]*gx + R[3]*gy + R[6]*gz;   // rot^T
        float ly = R[1]*gx + R[4]*gy + R[7]*gz;
        float lz = R[2]*gx + R[5]*gy + R[8]*gz;
        float* Fr = F + (size_t)n*960;
        Fr[192+hp] = lx; Fr[288+hp] = ly; Fr[384+hp] = lz;
        Fr[480+hp] = sqrtf(lx*lx+ly*ly+lz*lz + 1e-8f);
    }
    __syncthreads();
    if (t < TI*32) {
        int qq = t >> 5, d = t & 31;
        float acc = 0.f;
        #pragma unroll 8
        for (int c = 0; c < CZ; ++c) acc += sZd[qq][c] * wdz[(size_t)c*32 + d];
        sPz[qq][d] = acc + bdz[d];
    }
    __syncthreads();
    for (int e = t; e < TI*384; e += 256) {
        int qq = e/384, hd = e%384; int n = i0+qq;
        F[(size_t)n*960 + 576 + hd] = rs[(size_t)n*NH + (hd>>5)] * sPz[qq][hd&31];
    }
}

// =====================================================================
// Kernel D2: tiled GEMM  out[512][384] = F[512][960] @ w_out + b_out
// (R3-proven BM=64 BN=32 tile)
// =====================================================================
__global__ __launch_bounds__(256) void out_gemm_kernel(
    const float* __restrict__ w_out, const float* __restrict__ b_out,
    const float* __restrict__ ws, float* __restrict__ out)
{
    constexpr int BM=64, BN=32, BK=32, LDA=68;
    __shared__ float sA[BK][LDA];
    __shared__ float sB[BK][BN];
    const float* F = ws + OFF_F;
    const int m0 = blockIdx.x * BM;
    const int c0 = blockIdx.y * BN;
    const int t  = threadIdx.x;
    const int tx = t & 15, ty = t >> 4;

    float acc[4][2] = {};

    for (int kt = 0; kt < 960/BK; ++kt) {
        const int k0 = kt*BK;
        #pragma unroll
        for (int r = 0; r < 2; ++r) {
            int qd = r*256 + t;
            int m = qd >> 3, kq = (qd & 7) << 2;
            float4 f = *(const float4*)(F + (size_t)(m0+m)*960 + k0 + kq);
            sA[kq+0][m] = f.x; sA[kq+1][m] = f.y;
            sA[kq+2][m] = f.z; sA[kq+3][m] = f.w;
        }
        {
            int kk = t >> 3, c4 = (t & 7) << 2;
            float4 f = *(const float4*)(w_out + (size_t)(k0+kk)*CS + c0 + c4);
            *(float4*)&sB[kk][c4] = f;
        }
        __syncthreads();
        #pragma unroll
        for (int kk = 0; kk < BK; ++kk) {
            float4 a = *(const float4*)&sA[kk][ty*4];
            float2 b = *(const float2*)&sB[kk][tx*2];
            acc[0][0] += a.x*b.x; acc[0][1] += a.x*b.y;
            acc[1][0] += a.y*b.x; acc[1][1] += a.y*b.y;
            acc[2][0] += a.z*b.x; acc[2][1] += a.z*b.y;
            acc[3][0] += a.w*b.x; acc[3][1] += a.w*b.y;
        }
        __syncthreads();
    }

    #pragma unroll
    for (int i = 0; i < 4; ++i)
        #pragma unroll
        for (int j = 0; j < 2; ++j) {
            int n = m0 + ty*4 + i;
            int c = c0 + tx*2 + j;
            out[(size_t)n*CS + c] = acc[i][j] + b_out[c];
        }
}

// =====================================================================
extern "C" void kernel_launch(void* const* d_in, const int* in_sizes, int n_in,
                              void* d_out, int out_size, void* d_ws, size_t ws_size,
                              hipStream_t stream)
{
    const float* s     = (const float*)d_in[0];
    const float* z     = (const float*)d_in[1];
    const float* rot   = (const float*)d_in[2];
    const float* trans = (const float*)d_in[3];
    const float* mask  = (const float*)d_in[4];
    const int*   ridx  = (const int*)  d_in[5];
    const float* wq    = (const float*)d_in[6];
    const float* bq    = (const float*)d_in[7];
    const float* wkv   = (const float*)d_in[8];
    const float* bkv   = (const float*)d_in[9];
    const float* wqp   = (const float*)d_in[10];
    const float* bqp   = (const float*)d_in[11];
    const float* wkvp  = (const float*)d_in[12];
    const float* bkvp  = (const float*)d_in[13];
    const float* wb    = (const float*)d_in[14];
    const float* bb    = (const float*)d_in[15];
    const float* wdz   = (const float*)d_in[16];
    const float* bdz   = (const float*)d_in[17];
    const float* hw    = (const float*)d_in[18];
    const float* wout  = (const float*)d_in[19];
    const float* bout  = (const float*)d_in[20];
    float* ws  = (float*)d_ws;
    float* out = (float*)d_out;

    hipLaunchKernelGGL(proj_gemm_kernel, dim3(NRIG/64, 1152/32), dim3(256), 0, stream,
        s, wq,bq, wkv,bkv, wqp,bqp, wkvp,bkvp, ws);
    hipLaunchKernelGGL(rotate_kernel, dim3(NRIG*192/256), dim3(256), 0, stream,
        rot, trans, ws);
    hipLaunchKernelGGL(zwb_kernel, dim3(NPAIR/64), dim3(256), 0, stream,
        z, wb, bb, ws);
    hipLaunchKernelGGL(attn_kernel, dim3(NH, NRIG/4), dim3(256), 0, stream,
        hw, mask, ridx, ws);
    hipLaunchKernelGGL(feats_kernel, dim3(NRIG/4), dim3(256), 0, stream,
        rot, trans, z, ridx, wdz, bdz, ws);
    hipLaunchKernelGGL(out_gemm_kernel, dim3(NRIG/64, CS/32), dim3(256), 0, stream,
        wout, bout, ws, out);
}

// Round 7
// 125.956 us; speedup vs baseline: 1.0626x; 1.0103x over previous
//
#include <hip/hip_runtime.h>
#include <hip/hip_bf16.h>
#include <math.h>

// ---------------- problem constants (B=1) ----------------
constexpr int NRIG = 512;
constexpr int NRES = 448;
constexpr int CS   = 384;
constexpr int CZ   = 128;
constexpr int CH   = 16;
constexpr int NH   = 12;
constexpr int PQ   = 4;
constexpr int PV   = 8;
constexpr int HC   = NH * CH;        // 192
constexpr int NPAIR = NRES*NRES;     // 200704
constexpr float INF_ = 100000.0f;
constexpr float SC_ = 0.57735026918962584f;    // sqrt(1/3)

// ---------------- workspace layout (floats) ----------------
constexpr size_t OFF_Q   = 0;                                // [12][512][16]
constexpr size_t OFF_KT  = OFF_Q   + (size_t)NH*NRIG*16;     // [12][16][512]
constexpr size_t OFF_QP  = OFF_KT  + (size_t)NH*16*NRIG;     // [12][512][12]
constexpr size_t OFF_KPT = OFF_QP  + (size_t)NH*NRIG*12;     // [12][12][512]
constexpr size_t OFF_VT  = OFF_KPT + (size_t)NH*12*NRIG;     // [12][40][512]
constexpr size_t OFF_O   = OFF_VT  + (size_t)NH*40*NRIG;     // [512][12][16]
constexpr size_t OFF_OPT = OFF_O   + (size_t)NRIG*HC;        // [512][12][24]
constexpr size_t OFF_RS  = OFF_OPT + (size_t)NRIG*NH*PV*3;   // [512][12]
constexpr size_t OFF_BP  = OFF_RS  + (size_t)NRIG*NH;        // [12][200704]
constexpr size_t OFF_RAW = OFF_BP  + (size_t)NH*NPAIR;       // [512][576]
constexpr size_t OFF_F   = OFF_RAW + (size_t)NRIG*576;       // [512][960]
constexpr size_t OFF_P3  = OFF_F   + (size_t)NRIG*960;       // [3][512][384]

constexpr int ZWB_BLOCKS = NPAIR/128;   // 1568

// =====================================================================
// Kernel 1: prep = zwb2 (blocks [0,1568)) | proj_gemm (blocks [1568,1856))
// zwb2: bp[h][r] = (z[r,:].w_b[:,h] + b_b[h])*SC.  thread=row, wave=c-half,
//       w via uniform (SGPR) loads, z staged f4 + XOR swizzle.
// proj: C[512][1152] = s @ [wq|wkv|wqp|wkvp], epilogue scatters to Q/KT/VT/RAW.
// =====================================================================
__global__ __launch_bounds__(256) void prep_kernel(
    const float* __restrict__ z,  const float* __restrict__ wb, const float* __restrict__ bb,
    const float* __restrict__ s,
    const float* __restrict__ wq,  const float* __restrict__ bq,
    const float* __restrict__ wkv, const float* __restrict__ bkv,
    const float* __restrict__ wqp, const float* __restrict__ bqp,
    const float* __restrict__ wkvp,const float* __restrict__ bkvp,
    float* __restrict__ ws)
{
    __shared__ float smem[18560];       // zwb: sZ[128][132] + sRed[128][13]; proj: sA+sB
    const int t = threadIdx.x;

    if ((int)blockIdx.x < ZWB_BLOCKS) {
        // ---------------- zwb2 ----------------
        float* sZ   = smem;             // [128][132], XOR-swizzled f4 chunks
        float* sRed = smem + 16896;     // [128][13]
        const size_t r0 = (size_t)blockIdx.x * 128;
        #pragma unroll
        for (int k = 0; k < 16; ++k) {
            int i = k*256 + t;
            int row = i >> 5, c4 = i & 31;
            float4 f = *(const float4*)(z + (r0+row)*CZ + (c4<<2));
            *(float4*)&sZ[row*132 + ((c4 ^ (row&7))<<2)] = f;
        }
        __syncthreads();
        const int wid = t >> 6, lane = t & 63;
        const int rB = ((wid>>1)<<6) | lane;     // row in block
        const int ch = wid & 1;                  // c-half
        float acc[12] = {0,0,0,0,0,0,0,0,0,0,0,0};
        const int cb = ch*16;
        #pragma unroll
        for (int i = 0; i < 16; ++i) {
            const int c4 = cb + i;
            float4 zf = *(const float4*)&sZ[rB*132 + ((c4 ^ (rB&7))<<2)];
            #pragma unroll
            for (int e = 0; e < 4; ++e) {
                const float zv = (&zf.x)[e];
                const float* wr = wb + (c4*4+e)*12;     // uniform -> s_load
                #pragma unroll
                for (int h = 0; h < 12; ++h) acc[h] += zv * wr[h];
            }
        }
        if (ch == 0) {
            #pragma unroll
            for (int h = 0; h < 12; ++h) sRed[rB*13 + h] = acc[h];
        }
        __syncthreads();
        if (ch == 1) {
            float* bp = ws + OFF_BP;
            #pragma unroll
            for (int h = 0; h < 12; ++h) {
                float v = (acc[h] + sRed[rB*13 + h] + bb[h]) * SC_;
                bp[(size_t)h*NPAIR + r0 + rB] = v;
            }
        }
    } else {
        // ---------------- proj_gemm ----------------
        constexpr int BM=64, BN=32, BK=32, LDA=68;
        float (*sA)[LDA] = (float(*)[LDA])smem;          // [32][68]
        float (*sB)[BN]  = (float(*)[BN])(smem + 2176);  // [32][32]
        const int bid = (int)blockIdx.x - ZWB_BLOCKS;
        const int m0 = (bid & 7) * BM;
        const int c0 = (bid >> 3) * BN;
        const int tx = t & 15, ty = t >> 4;

        float acc[4][2] = {};
        for (int kt = 0; kt < CS/BK; ++kt) {
            const int k0 = kt*BK;
            #pragma unroll
            for (int r = 0; r < 2; ++r) {
                int qd = r*256 + t;
                int m = qd >> 3, kq = (qd & 7) << 2;
                float4 f = *(const float4*)(s + (size_t)(m0+m)*CS + k0 + kq);
                sA[kq+0][m] = f.x; sA[kq+1][m] = f.y;
                sA[kq+2][m] = f.z; sA[kq+3][m] = f.w;
            }
            {
                int kk = t >> 3, c4 = (t & 7) << 2;
                int c = c0 + c4;
                const float* wp; int ld, co;
                if (c < 192)      { wp = wq;   ld = 192; co = c;     }
                else if (c < 576) { wp = wkv;  ld = 384; co = c-192; }
                else if (c < 720) { wp = wqp;  ld = 144; co = c-576; }
                else              { wp = wkvp; ld = 432; co = c-720; }
                float4 f = *(const float4*)(wp + (size_t)(k0+kk)*ld + co);
                *(float4*)&sB[kk][c4] = f;
            }
            __syncthreads();
            #pragma unroll
            for (int kk = 0; kk < BK; ++kk) {
                float4 a = *(const float4*)&sA[kk][ty*4];
                float2 b = *(const float2*)&sB[kk][tx*2];
                acc[0][0] += a.x*b.x; acc[0][1] += a.x*b.y;
                acc[1][0] += a.y*b.x; acc[1][1] += a.y*b.y;
                acc[2][0] += a.z*b.x; acc[2][1] += a.z*b.y;
                acc[3][0] += a.w*b.x; acc[3][1] += a.w*b.y;
            }
            __syncthreads();
        }
        float* qw  = ws + OFF_Q;  float* ktw = ws + OFF_KT;  float* vt = ws + OFF_VT;
        float* raw = ws + OFF_RAW;
        #pragma unroll
        for (int i = 0; i < 4; ++i)
            #pragma unroll
            for (int j = 0; j < 2; ++j) {
                int n = m0 + ty*4 + i;
                int c = c0 + tx*2 + j;
                if (c < 192) {
                    int hh = c >> 4, cc = c & 15;
                    qw[((size_t)hh*NRIG + n)*16 + cc] = acc[i][j] + bq[c];
                } else if (c < 576) {
                    int e = c-192; float val = acc[i][j] + bkv[e];
                    int hh = e >> 5, sub = e & 31;
                    if (sub < CH) ktw[((size_t)hh*16 + sub)*NRIG + n] = val;
                    else          vt [((size_t)hh*40 + (sub-CH))*NRIG + n] = val;
                } else {
                    int e = c-576;
                    float bb_ = (c < 720) ? bqp[e] : bkvp[c-720];
                    raw[(size_t)n*576 + e] = acc[i][j] + bb_;
                }
            }
    }
}

// =====================================================================
// Kernel 2: rotate raw local points -> global frame
// =====================================================================
__global__ __launch_bounds__(256) void rotate_kernel(
    const float* __restrict__ rot, const float* __restrict__ trans,
    const float* __restrict__ raw_in, float* __restrict__ qpw,
    float* __restrict__ kptw, float* __restrict__ vtw)
{
    const int gid = blockIdx.x*256 + threadIdx.x;
    const int n = gid / 192, d = gid % 192;
    const float* raw = raw_in + (size_t)n*576;
    float px, py, pzz;
    if (d < 48) { px = raw[d];      py = raw[48+d];       pzz = raw[96+d]; }
    else { int dd = d-48; px = raw[144+dd]; py = raw[288+dd]; pzz = raw[432+dd]; }
    const float* R = rot   + (size_t)n*9;
    const float* T = trans + (size_t)n*3;
    float gx = R[0]*px + R[1]*py + R[2]*pzz + T[0];
    float gy = R[3]*px + R[4]*py + R[5]*pzz + T[1];
    float gz = R[6]*px + R[7]*py + R[8]*pzz + T[2];
    if (d < 48) {                              // q_pts: d = h*4+p
        int hh = d >> 2, pp = d & 3;
        float* dst = qpw + ((size_t)hh*NRIG + n)*12 + pp*3;
        dst[0]=gx; dst[1]=gy; dst[2]=gz;
    } else {
        int dd = d-48; int hh = dd/12, pp = dd%12;
        if (pp < PQ) {
            float* kpt = kptw + (size_t)hh*12*NRIG;
            kpt[(size_t)(pp*3+0)*NRIG + n] = gx;
            kpt[(size_t)(pp*3+1)*NRIG + n] = gy;
            kpt[(size_t)(pp*3+2)*NRIG + n] = gz;
        } else {
            float* vt = vtw + ((size_t)hh*40 + 16 + (pp-PQ)*3)*NRIG + n;
            vt[0*NRIG]=gx; vt[1*NRIG]=gy; vt[2*NRIG]=gz;
        }
    }
}

// =====================================================================
// Kernel 3: attention. block = (h, 8 queries), 256 threads.
// Q/QP/mask_i/ridx_i wave-uniform -> scalar loads. No max-subtraction
// (logits provably <= ~8). S folded into phase-2 as component 40.
// =====================================================================
__global__ __launch_bounds__(256) void attn_kernel(
    const float* __restrict__ hw_in, const float* __restrict__ mask,
    const int* __restrict__ ridx,
    const float* __restrict__ qw_all,  const float* __restrict__ ktw_all,
    const float* __restrict__ qpw_all, const float* __restrict__ kpt_all,
    const float* __restrict__ vt_all,  const float* __restrict__ bp_all,
    float* __restrict__ o_out, float* __restrict__ opt_out, float* __restrict__ rs_out)
{
    constexpr int TI = 8;
    const int h    = blockIdx.x;
    const int i0   = blockIdx.y * TI;
    const int t    = threadIdx.x;
    const int lane = t & 63, wid = t >> 6;

    __shared__ float sE[TI*516];        // [qq][516], b32 conflict-free
    __shared__ float sP[16][TI][45];    // partial sums [g][qq][comp]
    __shared__ float sS[TI];

    const float* qw  = qw_all  + (size_t)h*NRIG*16;
    const float* ktw = ktw_all + (size_t)h*16*NRIG;
    const float* qpw = qpw_all + (size_t)h*NRIG*12;
    const float* kpt = kpt_all + (size_t)h*12*NRIG;
    const float* vt  = vt_all  + (size_t)h*40*NRIG;
    const float* bph = bp_all  + (size_t)h*NPAIR;

    const float hwv = -0.5f * log1pf(__expf(hw_in[h])) * 0.13608276348795434f; // -0.5*softplus*sqrt(1/54)
    const float QKS = 0.14433756729740643f;                                    // sqrt(1/48)

    // ---------- phase 1: logits -> exp -> sE ----------
    #pragma unroll
    for (int jj = 0; jj < 2; ++jj) {
        const int j = t + jj*256;
        float kk[16], kpv[12];
        #pragma unroll
        for (int c = 0; c < 16; ++c) kk[c]  = ktw[c*NRIG + j];   // coalesced
        #pragma unroll
        for (int e = 0; e < 12; ++e) kpv[e] = kpt[e*NRIG + j];   // coalesced
        const float mj = mask[j];
        const int   rj = ridx[j];
        #pragma unroll
        for (int qq = 0; qq < TI; ++qq) {
            const float* qv  = qw  + (size_t)(i0+qq)*16;   // uniform -> s_load
            const float* qpv = qpw + (size_t)(i0+qq)*12;   // uniform -> s_load
            const float  mi  = mask[i0+qq];                // uniform
            const int    ri  = ridx[i0+qq];                // uniform
            float dot = 0.f;
            #pragma unroll
            for (int c = 0; c < 16; ++c) dot += qv[c]*kk[c];
            float sq = 0.f;
            #pragma unroll
            for (int e = 0; e < 12; ++e) { float d = qpv[e]-kpv[e]; sq += d*d; }
            const float bv = bph[(size_t)ri*NRES + rj];    // L1-hot 1.8KB row
            const float lgt = dot*QKS + bv + hwv*sq + INF_*(mi*mj - 1.0f);
            sE[qq*516 + j] = __expf(lgt);
        }
    }
    __syncthreads();

    // ---------- phase 2: output GEMM. wave wid owns comps c = wid + 4*ci ----------
    {
        float acc[11][TI];
        #pragma unroll
        for (int ci=0;ci<11;++ci)
            #pragma unroll
            for (int qq=0;qq<TI;++qq) acc[ci][qq]=0.f;

        #pragma unroll
        for (int m = 0; m < 8; ++m) {
            const int j = lane + (m<<6);
            float ev[TI];
            #pragma unroll
            for (int qq=0;qq<TI;++qq) ev[qq] = sE[qq*516 + j];
            #pragma unroll
            for (int ci = 0; ci < 11; ++ci) {
                if (ci < 10 || wid == 0) {
                    const int c = wid + (ci<<2);                       // 0..40
                    const float vv = (c == 40) ? 1.0f : vt[(size_t)c*NRIG + j];
                    #pragma unroll
                    for (int qq=0;qq<TI;++qq) acc[ci][qq] += ev[qq]*vv;
                }
            }
        }
        // xor1/xor2 (DPP, VALU-pipe) -> 16 partial groups
        #pragma unroll
        for (int ci=0;ci<11;++ci)
            if (ci < 10 || wid == 0)
                #pragma unroll
                for (int qq=0;qq<TI;++qq) {
                    acc[ci][qq] += __shfl_xor(acc[ci][qq], 1);
                    acc[ci][qq] += __shfl_xor(acc[ci][qq], 2);
                }
        if ((lane & 3) == 0) {
            const int g = lane >> 2;
            #pragma unroll
            for (int ci=0;ci<11;++ci)
                if (ci < 10 || wid == 0) {
                    const int c = wid + (ci<<2);
                    #pragma unroll
                    for (int qq=0;qq<TI;++qq) sP[g][qq][c] = acc[ci][qq];
                }
        }
    }
    __syncthreads();

    if (t < TI) {
        float S = 0.f;
        #pragma unroll
        for (int g = 0; g < 16; ++g) S += sP[g][t][40];
        sS[t] = S;
    }
    __syncthreads();

    // ---------- epilogue: 8*41 outputs ----------
    for (int e = t; e < TI*41; e += 256) {
        const int qq = e / 41, c = e % 41;
        const int n = i0 + qq;
        float sum = 0.f;
        #pragma unroll
        for (int g = 0; g < 16; ++g) sum += sP[g][qq][c];
        const float val = sum * (1.0f / sS[qq]);
        if (c < 16)       o_out[((size_t)n*NH + h)*CH + c]        = val;
        else if (c < 40)  opt_out[((size_t)n*NH + h)*24 + (c-16)] = val;
        else              rs_out[(size_t)n*NH + h]                = val;
    }
}

// =====================================================================
// Kernel 4: build feats F[512][960]; pz_diag computed in-block.
// =====================================================================
__global__ __launch_bounds__(256) void feats_kernel(
    const float* __restrict__ rot, const float* __restrict__ trans,
    const float* __restrict__ z, const int* __restrict__ ridx,
    const float* __restrict__ wdz, const float* __restrict__ bdz,
    const float* __restrict__ o_ws, const float* __restrict__ optg,
    const float* __restrict__ rs, float* __restrict__ F)
{
    constexpr int TI = 4;
    __shared__ float sZd[TI][CZ];
    __shared__ float sPz[TI][32];
    const int i0 = blockIdx.x*TI;
    const int t  = threadIdx.x;

    for (int e = t; e < TI*CZ; e += 256) {
        int qq = e >> 7, c = e & 127;
        int ri = ridx[i0+qq];
        sZd[qq][c] = z[((size_t)ri*NRES + ri)*CZ + c];
    }
    for (int e = t; e < TI*HC; e += 256) {
        int qq = e/HC, c = e%HC;
        F[(size_t)(i0+qq)*960 + c] = o_ws[(size_t)(i0+qq)*HC + c];
    }
    for (int e = t; e < TI*96; e += 256) {
        int qq = e/96, hp = e%96; int n = i0+qq;
        const float* g = optg + ((size_t)n*NH + hp/PV)*24 + (hp%PV)*3;
        float gx = g[0]-trans[n*3+0], gy = g[1]-trans[n*3+1], gz = g[2]-trans[n*3+2];
        const float* R = rot + (size_t)n*9;
        float lx = R[0]*gx + R[3]*gy + R[6]*gz;   // rot^T
        float ly = R[1]*gx + R[4]*gy + R[7]*gz;
        float lz = R[2]*gx + R[5]*gy + R[8]*gz;
        float* Fr = F + (size_t)n*960;
        Fr[192+hp] = lx; Fr[288+hp] = ly; Fr[384+hp] = lz;
        Fr[480+hp] = sqrtf(lx*lx+ly*ly+lz*lz + 1e-8f);
    }
    __syncthreads();
    if (t < TI*32) {
        int qq = t >> 5, d = t & 31;
        float acc = 0.f;
        #pragma unroll 8
        for (int c = 0; c < CZ; ++c) acc += sZd[qq][c] * wdz[(size_t)c*32 + d];
        sPz[qq][d] = acc + bdz[d];
    }
    __syncthreads();
    for (int e = t; e < TI*384; e += 256) {
        int qq = e/384, hd = e%384; int n = i0+qq;
        F[(size_t)n*960 + 576 + hd] = rs[(size_t)n*NH + (hd>>5)] * sPz[qq][hd&31];
    }
}

// =====================================================================
// Kernel 5: split-K GEMM  P[ks][512][384] = F[:, ks*320..+320] @ w_out-slice
// grid (8, 12, 3)
// =====================================================================
__global__ __launch_bounds__(256) void out_gemm_kernel(
    const float* __restrict__ w_out, const float* __restrict__ F,
    float* __restrict__ P)
{
    constexpr int BM=64, BN=32, BK=32, LDA=68;
    __shared__ float sA[BK][LDA];
    __shared__ float sB[BK][BN];
    const int m0 = blockIdx.x * BM;
    const int c0 = blockIdx.y * BN;
    const int ks = blockIdx.z;
    const int t  = threadIdx.x;
    const int tx = t & 15, ty = t >> 4;

    float acc[4][2] = {};
    for (int kt = 0; kt < 10; ++kt) {
        const int k0 = ks*320 + kt*BK;
        #pragma unroll
        for (int r = 0; r < 2; ++r) {
            int qd = r*256 + t;
            int m = qd >> 3, kq = (qd & 7) << 2;
            float4 f = *(const float4*)(F + (size_t)(m0+m)*960 + k0 + kq);
            sA[kq+0][m] = f.x; sA[kq+1][m] = f.y;
            sA[kq+2][m] = f.z; sA[kq+3][m] = f.w;
        }
        {
            int kk = t >> 3, c4 = (t & 7) << 2;
            float4 f = *(const float4*)(w_out + (size_t)(k0+kk)*CS + c0 + c4);
            *(float4*)&sB[kk][c4] = f;
        }
        __syncthreads();
        #pragma unroll
        for (int kk = 0; kk < BK; ++kk) {
            float4 a = *(const float4*)&sA[kk][ty*4];
            float2 b = *(const float2*)&sB[kk][tx*2];
            acc[0][0] += a.x*b.x; acc[0][1] += a.x*b.y;
            acc[1][0] += a.y*b.x; acc[1][1] += a.y*b.y;
            acc[2][0] += a.z*b.x; acc[2][1] += a.z*b.y;
            acc[3][0] += a.w*b.x; acc[3][1] += a.w*b.y;
        }
        __syncthreads();
    }
    #pragma unroll
    for (int i = 0; i < 4; ++i)
        #pragma unroll
        for (int j = 0; j < 2; ++j) {
            int n = m0 + ty*4 + i;
            int c = c0 + tx*2 + j;
            P[(size_t)ks*NRIG*CS + (size_t)n*CS + c] = acc[i][j];
        }
}

// =====================================================================
// Kernel 6: reduce split-K partials + bias
// =====================================================================
__global__ __launch_bounds__(256) void reduce_kernel(
    const float* __restrict__ P, const float* __restrict__ b_out,
    float* __restrict__ out)
{
    const int i4 = blockIdx.x*256 + threadIdx.x;          // f4 index, 49152 total
    const size_t base = (size_t)i4 * 4;
    float4 a = *(const float4*)(P + base);
    float4 b = *(const float4*)(P + (size_t)NRIG*CS + base);
    float4 c = *(const float4*)(P + (size_t)2*NRIG*CS + base);
    const int cc = (int)(base % CS);
    float4 bv = *(const float4*)(b_out + cc);
    float4 r;
    r.x = a.x+b.x+c.x+bv.x; r.y = a.y+b.y+c.y+bv.y;
    r.z = a.z+b.z+c.z+bv.z; r.w = a.w+b.w+c.w+bv.w;
    *(float4*)(out + base) = r;
}

// =====================================================================
extern "C" void kernel_launch(void* const* d_in, const int* in_sizes, int n_in,
                              void* d_out, int out_size, void* d_ws, size_t ws_size,
                              hipStream_t stream)
{
    const float* s     = (const float*)d_in[0];
    const float* z     = (const float*)d_in[1];
    const float* rot   = (const float*)d_in[2];
    const float* trans = (const float*)d_in[3];
    const float* mask  = (const float*)d_in[4];
    const int*   ridx  = (const int*)  d_in[5];
    const float* wq    = (const float*)d_in[6];
    const float* bq    = (const float*)d_in[7];
    const float* wkv   = (const float*)d_in[8];
    const float* bkv   = (const float*)d_in[9];
    const float* wqp   = (const float*)d_in[10];
    const float* bqp   = (const float*)d_in[11];
    const float* wkvp  = (const float*)d_in[12];
    const float* bkvp  = (const float*)d_in[13];
    const float* wb    = (const float*)d_in[14];
    const float* bb    = (const float*)d_in[15];
    const float* wdz   = (const float*)d_in[16];
    const float* bdz   = (const float*)d_in[17];
    const float* hw    = (const float*)d_in[18];
    const float* wout  = (const float*)d_in[19];
    const float* bout  = (const float*)d_in[20];
    float* ws  = (float*)d_ws;
    float* out = (float*)d_out;

    hipLaunchKernelGGL(prep_kernel, dim3(ZWB_BLOCKS + 288), dim3(256), 0, stream,
        z, wb, bb, s, wq,bq, wkv,bkv, wqp,bqp, wkvp,bkvp, ws);
    hipLaunchKernelGGL(rotate_kernel, dim3(NRIG*192/256), dim3(256), 0, stream,
        rot, trans, ws+OFF_RAW, ws+OFF_QP, ws+OFF_KPT, ws+OFF_VT);
    hipLaunchKernelGGL(attn_kernel, dim3(NH, NRIG/8), dim3(256), 0, stream,
        hw, mask, ridx, ws+OFF_Q, ws+OFF_KT, ws+OFF_QP, ws+OFF_KPT,
        ws+OFF_VT, ws+OFF_BP, ws+OFF_O, ws+OFF_OPT, ws+OFF_RS);
    hipLaunchKernelGGL(feats_kernel, dim3(NRIG/4), dim3(256), 0, stream,
        rot, trans, z, ridx, wdz, bdz, ws+OFF_O, ws+OFF_OPT, ws+OFF_RS, ws+OFF_F);
    hipLaunchKernelGGL(out_gemm_kernel, dim3(NRIG/64, CS/32, 3), dim3(256), 0, stream,
        wout, ws+OFF_F, ws+OFF_P3);
    hipLaunchKernelGGL(reduce_kernel, dim3(NRIG*CS/4/256), dim3(256), 0, stream,
        ws+OFF_P3, bout, out);
}

// Round 8
// 124.719 us; speedup vs baseline: 1.0731x; 1.0099x over previous
//
#include <hip/hip_runtime.h>
#include <hip/hip_bf16.h>
#include <math.h>

// ---------------- problem constants (B=1) ----------------
constexpr int NRIG = 512;
constexpr int NRES = 448;
constexpr int CS   = 384;
constexpr int CZ   = 128;
constexpr int CH   = 16;
constexpr int NH   = 12;
constexpr int PQ   = 4;
constexpr int PV   = 8;
constexpr int HC   = NH * CH;        // 192
constexpr int NPAIR = NRES*NRES;     // 200704
constexpr float INF_ = 100000.0f;
constexpr float SC_ = 0.57735026918962584f;    // sqrt(1/3)

// ---------------- workspace layout (floats) ----------------
constexpr size_t OFF_Q   = 0;                                // [12][512][16]
constexpr size_t OFF_KT  = OFF_Q   + (size_t)NH*NRIG*16;     // [12][16][512]
constexpr size_t OFF_QP  = OFF_KT  + (size_t)NH*16*NRIG;     // [12][512][12]
constexpr size_t OFF_KPT = OFF_QP  + (size_t)NH*NRIG*12;     // [12][12][512]
constexpr size_t OFF_VT  = OFF_KPT + (size_t)NH*12*NRIG;     // [12][40][512]
constexpr size_t OFF_O   = OFF_VT  + (size_t)NH*40*NRIG;     // [512][12][16]
constexpr size_t OFF_OPT = OFF_O   + (size_t)NRIG*HC;        // [512][12][24]
constexpr size_t OFF_RS  = OFF_OPT + (size_t)NRIG*NH*PV*3;   // [512][12]
constexpr size_t OFF_BP  = OFF_RS  + (size_t)NRIG*NH;        // [12][200704]
constexpr size_t OFF_RAW = OFF_BP  + (size_t)NH*NPAIR;       // [512][576]
constexpr size_t OFF_F   = OFF_RAW + (size_t)NRIG*576;       // [512][960]
constexpr size_t OFF_P3  = OFF_F   + (size_t)NRIG*960;       // [3][512][384]

constexpr int ZWB_BLOCKS = NPAIR/128;   // 1568

// =====================================================================
// Kernel 1: prep = zwb2 (blocks [0,1568)) | proj_gemm (blocks [1568,1856))
// zwb2: bp[h][r] = (z[r,:].w_b[:,h] + b_b[h])*SC.  thread=row, wave=c-half,
//       w via uniform (SGPR) loads, z staged f4 + XOR swizzle.
// proj: C[512][1152] = s @ [wq|wkv|wqp|wkvp], epilogue scatters to Q/KT/VT/RAW.
// =====================================================================
__global__ __launch_bounds__(256) void prep_kernel(
    const float* __restrict__ z,  const float* __restrict__ wb, const float* __restrict__ bb,
    const float* __restrict__ s,
    const float* __restrict__ wq,  const float* __restrict__ bq,
    const float* __restrict__ wkv, const float* __restrict__ bkv,
    const float* __restrict__ wqp, const float* __restrict__ bqp,
    const float* __restrict__ wkvp,const float* __restrict__ bkvp,
    float* __restrict__ ws)
{
    __shared__ float smem[18560];       // zwb: sZ[128][132] + sRed[128][13]; proj: sA+sB
    const int t = threadIdx.x;

    if ((int)blockIdx.x < ZWB_BLOCKS) {
        // ---------------- zwb2 ----------------
        float* sZ   = smem;             // [128][132], XOR-swizzled f4 chunks
        float* sRed = smem + 16896;     // [128][13]
        const size_t r0 = (size_t)blockIdx.x * 128;
        #pragma unroll
        for (int k = 0; k < 16; ++k) {
            int i = k*256 + t;
            int row = i >> 5, c4 = i & 31;
            float4 f = *(const float4*)(z + (r0+row)*CZ + (c4<<2));
            *(float4*)&sZ[row*132 + ((c4 ^ (row&7))<<2)] = f;
        }
        __syncthreads();
        const int wid = t >> 6, lane = t & 63;
        const int rB = ((wid>>1)<<6) | lane;     // row in block
        const int ch = wid & 1;                  // c-half
        float acc[12] = {0,0,0,0,0,0,0,0,0,0,0,0};
        const int cb = ch*16;
        #pragma unroll
        for (int i = 0; i < 16; ++i) {
            const int c4 = cb + i;
            float4 zf = *(const float4*)&sZ[rB*132 + ((c4 ^ (rB&7))<<2)];
            #pragma unroll
            for (int e = 0; e < 4; ++e) {
                const float zv = (&zf.x)[e];
                const float* wr = wb + (c4*4+e)*12;     // uniform -> s_load
                #pragma unroll
                for (int h = 0; h < 12; ++h) acc[h] += zv * wr[h];
            }
        }
        if (ch == 0) {
            #pragma unroll
            for (int h = 0; h < 12; ++h) sRed[rB*13 + h] = acc[h];
        }
        __syncthreads();
        if (ch == 1) {
            float* bp = ws + OFF_BP;
            #pragma unroll
            for (int h = 0; h < 12; ++h) {
                float v = (acc[h] + sRed[rB*13 + h] + bb[h]) * SC_;
                bp[(size_t)h*NPAIR + r0 + rB] = v;
            }
        }
    } else {
        // ---------------- proj_gemm ----------------
        constexpr int BM=64, BN=32, BK=32, LDA=68;
        float (*sA)[LDA] = (float(*)[LDA])smem;          // [32][68]
        float (*sB)[BN]  = (float(*)[BN])(smem + 2176);  // [32][32]
        const int bid = (int)blockIdx.x - ZWB_BLOCKS;
        const int m0 = (bid & 7) * BM;
        const int c0 = (bid >> 3) * BN;
        const int tx = t & 15, ty = t >> 4;

        float acc[4][2] = {};
        for (int kt = 0; kt < CS/BK; ++kt) {
            const int k0 = kt*BK;
            #pragma unroll
            for (int r = 0; r < 2; ++r) {
                int qd = r*256 + t;
                int m = qd >> 3, kq = (qd & 7) << 2;
                float4 f = *(const float4*)(s + (size_t)(m0+m)*CS + k0 + kq);
                sA[kq+0][m] = f.x; sA[kq+1][m] = f.y;
                sA[kq+2][m] = f.z; sA[kq+3][m] = f.w;
            }
            {
                int kk = t >> 3, c4 = (t & 7) << 2;
                int c = c0 + c4;
                const float* wp; int ld, co;
                if (c < 192)      { wp = wq;   ld = 192; co = c;     }
                else if (c < 576) { wp = wkv;  ld = 384; co = c-192; }
                else if (c < 720) { wp = wqp;  ld = 144; co = c-576; }
                else              { wp = wkvp; ld = 432; co = c-720; }
                float4 f = *(const float4*)(wp + (size_t)(k0+kk)*ld + co);
                *(float4*)&sB[kk][c4] = f;
            }
            __syncthreads();
            #pragma unroll
            for (int kk = 0; kk < BK; ++kk) {
                float4 a = *(const float4*)&sA[kk][ty*4];
                float2 b = *(const float2*)&sB[kk][tx*2];
                acc[0][0] += a.x*b.x; acc[0][1] += a.x*b.y;
                acc[1][0] += a.y*b.x; acc[1][1] += a.y*b.y;
                acc[2][0] += a.z*b.x; acc[2][1] += a.z*b.y;
                acc[3][0] += a.w*b.x; acc[3][1] += a.w*b.y;
            }
            __syncthreads();
        }
        float* qw  = ws + OFF_Q;  float* ktw = ws + OFF_KT;  float* vt = ws + OFF_VT;
        float* raw = ws + OFF_RAW;
        #pragma unroll
        for (int i = 0; i < 4; ++i)
            #pragma unroll
            for (int j = 0; j < 2; ++j) {
                int n = m0 + ty*4 + i;
                int c = c0 + tx*2 + j;
                if (c < 192) {
                    int hh = c >> 4, cc = c & 15;
                    qw[((size_t)hh*NRIG + n)*16 + cc] = acc[i][j] + bq[c];
                } else if (c < 576) {
                    int e = c-192; float val = acc[i][j] + bkv[e];
                    int hh = e >> 5, sub = e & 31;
                    if (sub < CH) ktw[((size_t)hh*16 + sub)*NRIG + n] = val;
                    else          vt [((size_t)hh*40 + (sub-CH))*NRIG + n] = val;
                } else {
                    int e = c-576;
                    float bb_ = (c < 720) ? bqp[e] : bkvp[c-720];
                    raw[(size_t)n*576 + e] = acc[i][j] + bb_;
                }
            }
    }
}

// =====================================================================
// Kernel 2: rotate raw local points -> global frame
// =====================================================================
__global__ __launch_bounds__(256) void rotate_kernel(
    const float* __restrict__ rot, const float* __restrict__ trans,
    const float* __restrict__ raw_in, float* __restrict__ qpw,
    float* __restrict__ kptw, float* __restrict__ vtw)
{
    const int gid = blockIdx.x*256 + threadIdx.x;
    const int n = gid / 192, d = gid % 192;
    const float* raw = raw_in + (size_t)n*576;
    float px, py, pzz;
    if (d < 48) { px = raw[d];      py = raw[48+d];       pzz = raw[96+d]; }
    else { int dd = d-48; px = raw[144+dd]; py = raw[288+dd]; pzz = raw[432+dd]; }
    const float* R = rot   + (size_t)n*9;
    const float* T = trans + (size_t)n*3;
    float gx = R[0]*px + R[1]*py + R[2]*pzz + T[0];
    float gy = R[3]*px + R[4]*py + R[5]*pzz + T[1];
    float gz = R[6]*px + R[7]*py + R[8]*pzz + T[2];
    if (d < 48) {                              // q_pts: d = h*4+p
        int hh = d >> 2, pp = d & 3;
        float* dst = qpw + ((size_t)hh*NRIG + n)*12 + pp*3;
        dst[0]=gx; dst[1]=gy; dst[2]=gz;
    } else {
        int dd = d-48; int hh = dd/12, pp = dd%12;
        if (pp < PQ) {
            float* kpt = kptw + (size_t)hh*12*NRIG;
            kpt[(size_t)(pp*3+0)*NRIG + n] = gx;
            kpt[(size_t)(pp*3+1)*NRIG + n] = gy;
            kpt[(size_t)(pp*3+2)*NRIG + n] = gz;
        } else {
            float* vt = vtw + ((size_t)hh*40 + 16 + (pp-PQ)*3)*NRIG + n;
            vt[0*NRIG]=gx; vt[1*NRIG]=gy; vt[2*NRIG]=gz;
        }
    }
}

// =====================================================================
// Kernel 3: attention. block = (h, 8 queries), 256 threads.
// Q/QP/mask_i/ridx_i wave-uniform -> scalar loads. No max-subtraction
// (logits provably <= ~8). S folded into phase-2 as component 40.
// =====================================================================
__global__ __launch_bounds__(256) void attn_kernel(
    const float* __restrict__ hw_in, const float* __restrict__ mask,
    const int* __restrict__ ridx,
    const float* __restrict__ qw_all,  const float* __restrict__ ktw_all,
    const float* __restrict__ qpw_all, const float* __restrict__ kpt_all,
    const float* __restrict__ vt_all,  const float* __restrict__ bp_all,
    float* __restrict__ o_out, float* __restrict__ opt_out, float* __restrict__ rs_out)
{
    constexpr int TI = 8;
    const int h    = blockIdx.x;
    const int i0   = blockIdx.y * TI;
    const int t    = threadIdx.x;
    const int lane = t & 63, wid = t >> 6;

    __shared__ float sE[TI*516];        // [qq][516], b32 conflict-free
    __shared__ float sP[16][TI][45];    // partial sums [g][qq][comp]
    __shared__ float sS[TI];

    const float* qw  = qw_all  + (size_t)h*NRIG*16;
    const float* ktw = ktw_all + (size_t)h*16*NRIG;
    const float* qpw = qpw_all + (size_t)h*NRIG*12;
    const float* kpt = kpt_all + (size_t)h*12*NRIG;
    const float* vt  = vt_all  + (size_t)h*40*NRIG;
    const float* bph = bp_all  + (size_t)h*NPAIR;

    const float hwv = -0.5f * log1pf(__expf(hw_in[h])) * 0.13608276348795434f; // -0.5*softplus*sqrt(1/54)
    const float QKS = 0.14433756729740643f;                                    // sqrt(1/48)

    // ---------- phase 1: logits -> exp -> sE ----------
    #pragma unroll
    for (int jj = 0; jj < 2; ++jj) {
        const int j = t + jj*256;
        float kk[16], kpv[12];
        #pragma unroll
        for (int c = 0; c < 16; ++c) kk[c]  = ktw[c*NRIG + j];   // coalesced
        #pragma unroll
        for (int e = 0; e < 12; ++e) kpv[e] = kpt[e*NRIG + j];   // coalesced
        const float mj = mask[j];
        const int   rj = ridx[j];
        #pragma unroll
        for (int qq = 0; qq < TI; ++qq) {
            const float* qv  = qw  + (size_t)(i0+qq)*16;   // uniform -> s_load
            const float* qpv = qpw + (size_t)(i0+qq)*12;   // uniform -> s_load
            const float  mi  = mask[i0+qq];                // uniform
            const int    ri  = ridx[i0+qq];                // uniform
            float dot = 0.f;
            #pragma unroll
            for (int c = 0; c < 16; ++c) dot += qv[c]*kk[c];
            float sq = 0.f;
            #pragma unroll
            for (int e = 0; e < 12; ++e) { float d = qpv[e]-kpv[e]; sq += d*d; }
            const float bv = bph[(size_t)ri*NRES + rj];    // L1-hot 1.8KB row
            const float lgt = dot*QKS + bv + hwv*sq + INF_*(mi*mj - 1.0f);
            sE[qq*516 + j] = __expf(lgt);
        }
    }
    __syncthreads();

    // ---------- phase 2: output GEMM. wave wid owns comps c = wid + 4*ci ----------
    {
        float acc[11][TI];
        #pragma unroll
        for (int ci=0;ci<11;++ci)
            #pragma unroll
            for (int qq=0;qq<TI;++qq) acc[ci][qq]=0.f;

        #pragma unroll
        for (int m = 0; m < 8; ++m) {
            const int j = lane + (m<<6);
            float ev[TI];
            #pragma unroll
            for (int qq=0;qq<TI;++qq) ev[qq] = sE[qq*516 + j];
            #pragma unroll
            for (int ci = 0; ci < 11; ++ci) {
                if (ci < 10 || wid == 0) {
                    const int c = wid + (ci<<2);                       // 0..40
                    const float vv = (c == 40) ? 1.0f : vt[(size_t)c*NRIG + j];
                    #pragma unroll
                    for (int qq=0;qq<TI;++qq) acc[ci][qq] += ev[qq]*vv;
                }
            }
        }
        // xor1/xor2 (DPP, VALU-pipe) -> 16 partial groups
        #pragma unroll
        for (int ci=0;ci<11;++ci)
            if (ci < 10 || wid == 0)
                #pragma unroll
                for (int qq=0;qq<TI;++qq) {
                    acc[ci][qq] += __shfl_xor(acc[ci][qq], 1);
                    acc[ci][qq] += __shfl_xor(acc[ci][qq], 2);
                }
        if ((lane & 3) == 0) {
            const int g = lane >> 2;
            #pragma unroll
            for (int ci=0;ci<11;++ci)
                if (ci < 10 || wid == 0) {
                    const int c = wid + (ci<<2);
                    #pragma unroll
                    for (int qq=0;qq<TI;++qq) sP[g][qq][c] = acc[ci][qq];
                }
        }
    }
    __syncthreads();

    if (t < TI) {
        float S = 0.f;
        #pragma unroll
        for (int g = 0; g < 16; ++g) S += sP[g][t][40];
        sS[t] = S;
    }
    __syncthreads();

    // ---------- epilogue: 8*41 outputs ----------
    for (int e = t; e < TI*41; e += 256) {
        const int qq = e / 41, c = e % 41;
        const int n = i0 + qq;
        float sum = 0.f;
        #pragma unroll
        for (int g = 0; g < 16; ++g) sum += sP[g][qq][c];
        const float val = sum * (1.0f / sS[qq]);
        if (c < 16)       o_out[((size_t)n*NH + h)*CH + c]        = val;
        else if (c < 40)  opt_out[((size_t)n*NH + h)*24 + (c-16)] = val;
        else              rs_out[(size_t)n*NH + h]                = val;
    }
}

// =====================================================================
// Kernel 4: build feats F[512][960]; pz_diag computed in-block.
// =====================================================================
__global__ __launch_bounds__(256) void feats_kernel(
    const float* __restrict__ rot, const float* __restrict__ trans,
    const float* __restrict__ z, const int* __restrict__ ridx,
    const float* __restrict__ wdz, const float* __restrict__ bdz,
    const float* __restrict__ o_ws, const float* __restrict__ optg,
    const float* __restrict__ rs, float* __restrict__ F)
{
    constexpr int TI = 4;
    __shared__ float sZd[TI][CZ];
    __shared__ float sPz[TI][32];
    const int i0 = blockIdx.x*TI;
    const int t  = threadIdx.x;

    for (int e = t; e < TI*CZ; e += 256) {
        int qq = e >> 7, c = e & 127;
        int ri = ridx[i0+qq];
        sZd[qq][c] = z[((size_t)ri*NRES + ri)*CZ + c];
    }
    for (int e = t; e < TI*HC; e += 256) {
        int qq = e/HC, c = e%HC;
        F[(size_t)(i0+qq)*960 + c] = o_ws[(size_t)(i0+qq)*HC + c];
    }
    for (int e = t; e < TI*96; e += 256) {
        int qq = e/96, hp = e%96; int n = i0+qq;
        const float* g = optg + ((size_t)n*NH + hp/PV)*24 + (hp%PV)*3;
        float gx = g[0]-trans[n*3+0], gy = g[1]-trans[n*3+1], gz = g[2]-trans[n*3+2];
        const float* R = rot + (size_t)n*9;
        float lx = R[0]*gx + R[3]*gy + R[6]*gz;   // rot^T
        float ly = R[1]*gx + R[4]*gy + R[7]*gz;
        float lz = R[2]*gx + R[5]*gy + R[8]*gz;
        float* Fr = F + (size_t)n*960;
        Fr[192+hp] = lx; Fr[288+hp] = ly; Fr[384+hp] = lz;
        Fr[480+hp] = sqrtf(lx*lx+ly*ly+lz*lz + 1e-8f);
    }
    __syncthreads();
    if (t < TI*32) {
        int qq = t >> 5, d = t & 31;
        float acc = 0.f;
        #pragma unroll 8
        for (int c = 0; c < CZ; ++c) acc += sZd[qq][c] * wdz[(size_t)c*32 + d];
        sPz[qq][d] = acc + bdz[d];
    }
    __syncthreads();
    for (int e = t; e < TI*384; e += 256) {
        int qq = e/384, hd = e%384; int n = i0+qq;
        F[(size_t)n*960 + 576 + hd] = rs[(size_t)n*NH + (hd>>5)] * sPz[qq][hd&31];
    }
}

// =====================================================================
// Kernel 5: split-K GEMM  P[ks][512][384] = F[:, ks*320..+320] @ w_out-slice
// grid (8, 12, 3)
// =====================================================================
__global__ __launch_bounds__(256) void out_gemm_kernel(
    const float* __restrict__ w_out, const float* __restrict__ F,
    float* __restrict__ P)
{
    constexpr int BM=64, BN=32, BK=32, LDA=68;
    __shared__ float sA[BK][LDA];
    __shared__ float sB[BK][BN];
    const int m0 = blockIdx.x * BM;
    const int c0 = blockIdx.y * BN;
    const int ks = blockIdx.z;
    const int t  = threadIdx.x;
    const int tx = t & 15, ty = t >> 4;

    float acc[4][2] = {};
    for (int kt = 0; kt < 10; ++kt) {
        const int k0 = ks*320 + kt*BK;
        #pragma unroll
        for (int r = 0; r < 2; ++r) {
            int qd = r*256 + t;
            int m = qd >> 3, kq = (qd & 7) << 2;
            float4 f = *(const float4*)(F + (size_t)(m0+m)*960 + k0 + kq);
            sA[kq+0][m] = f.x; sA[kq+1][m] = f.y;
            sA[kq+2][m] = f.z; sA[kq+3][m] = f.w;
        }
        {
            int kk = t >> 3, c4 = (t & 7) << 2;
            float4 f = *(const float4*)(w_out + (size_t)(k0+kk)*CS + c0 + c4);
            *(float4*)&sB[kk][c4] = f;
        }
        __syncthreads();
        #pragma unroll
        for (int kk = 0; kk < BK; ++kk) {
            float4 a = *(const float4*)&sA[kk][ty*4];
            float2 b = *(const float2*)&sB[kk][tx*2];
            acc[0][0] += a.x*b.x; acc[0][1] += a.x*b.y;
            acc[1][0] += a.y*b.x; acc[1][1] += a.y*b.y;
            acc[2][0] += a.z*b.x; acc[2][1] += a.z*b.y;
            acc[3][0] += a.w*b.x; acc[3][1] += a.w*b.y;
        }
        __syncthreads();
    }
    #pragma unroll
    for (int i = 0; i < 4; ++i)
        #pragma unroll
        for (int j = 0; j < 2; ++j) {
            int n = m0 + ty*4 + i;
            int c = c0 + tx*2 + j;
            P[(size_t)ks*NRIG*CS + (size_t)n*CS + c] = acc[i][j];
        }
}

// =====================================================================
// Kernel 6: reduce split-K partials + bias
// =====================================================================
__global__ __launch_bounds__(256) void reduce_kernel(
    const float* __restrict__ P, const float* __restrict__ b_out,
    float* __restrict__ out)
{
    const int i4 = blockIdx.x*256 + threadIdx.x;          // f4 index, 49152 total
    const size_t base = (size_t)i4 * 4;
    float4 a = *(const float4*)(P + base);
    float4 b = *(const float4*)(P + (size_t)NRIG*CS + base);
    float4 c = *(const float4*)(P + (size_t)2*NRIG*CS + base);
    const int cc = (int)(base % CS);
    float4 bv = *(const float4*)(b_out + cc);
    float4 r;
    r.x = a.x+b.x+c.x+bv.x; r.y = a.y+b.y+c.y+bv.y;
    r.z = a.z+b.z+c.z+bv.z; r.w = a.w+b.w+c.w+bv.w;
    *(float4*)(out + base) = r;
}

// =====================================================================
extern "C" void kernel_launch(void* const* d_in, const int* in_sizes, int n_in,
                              void* d_out, int out_size, void* d_ws, size_t ws_size,
                              hipStream_t stream)
{
    const float* s     = (const float*)d_in[0];
    const float* z     = (const float*)d_in[1];
    const float* rot   = (const float*)d_in[2];
    const float* trans = (const float*)d_in[3];
    const float* mask  = (const float*)d_in[4];
    const int*   ridx  = (const int*)  d_in[5];
    const float* wq    = (const float*)d_in[6];
    const float* bq    = (const float*)d_in[7];
    const float* wkv   = (const float*)d_in[8];
    const float* bkv   = (const float*)d_in[9];
    const float* wqp   = (const float*)d_in[10];
    const float* bqp   = (const float*)d_in[11];
    const float* wkvp  = (const float*)d_in[12];
    const float* bkvp  = (const float*)d_in[13];
    const float* wb    = (const float*)d_in[14];
    const float* bb    = (const float*)d_in[15];
    const float* wdz   = (const float*)d_in[16];
    const float* bdz   = (const float*)d_in[17];
    const float* hw    = (const float*)d_in[18];
    const float* wout  = (const float*)d_in[19];
    const float* bout  = (const float*)d_in[20];
    float* ws  = (float*)d_ws;
    float* out = (float*)d_out;

    hipLaunchKernelGGL(prep_kernel, dim3(ZWB_BLOCKS + 288), dim3(256), 0, stream,
        z, wb, bb, s, wq,bq, wkv,bkv, wqp,bqp, wkvp,bkvp, ws);
    hipLaunchKernelGGL(rotate_kernel, dim3(NRIG*192/256), dim3(256), 0, stream,
        rot, trans, ws+OFF_RAW, ws+OFF_QP, ws+OFF_KPT, ws+OFF_VT);
    hipLaunchKernelGGL(attn_kernel, dim3(NH, NRIG/8), dim3(256), 0, stream,
        hw, mask, ridx, ws+OFF_Q, ws+OFF_KT, ws+OFF_QP, ws+OFF_KPT,
        ws+OFF_VT, ws+OFF_BP, ws+OFF_O, ws+OFF_OPT, ws+OFF_RS);
    hipLaunchKernelGGL(feats_kernel, dim3(NRIG/4), dim3(256), 0, stream,
        rot, trans, z, ridx, wdz, bdz, ws+OFF_O, ws+OFF_OPT, ws+OFF_RS, ws+OFF_F);
    hipLaunchKernelGGL(out_gemm_kernel, dim3(NRIG/64, CS/32, 3), dim3(256), 0, stream,
        wout, ws+OFF_F, ws+OFF_P3);
    hipLaunchKernelGGL(reduce_kernel, dim3(NRIG*CS/4/256), dim3(256), 0, stream,
        ws+OFF_P3, bout, out);
}